// Round 1
// baseline (322.708 us; speedup 1.0000x reference)
//
#include <hip/hip_runtime.h>
#include <hip/hip_bf16.h>
#include <stdint.h>

#define N_EMBD 1024
#define N_HEAD 16
#define HEAD_DIM 64
#define T_SEQ 2048
#define BATCH 2
#define M_TOK (BATCH * T_SEQ)  // 4096

typedef short bf16x8 __attribute__((ext_vector_type(8)));
typedef float f32x4 __attribute__((ext_vector_type(4)));

__device__ __forceinline__ void gload_lds16(const void* g, void* l) {
  __builtin_amdgcn_global_load_lds(
      (const __attribute__((address_space(1))) void*)g,
      (__attribute__((address_space(3))) void*)l, 16, 0, 0);
}

__device__ __forceinline__ uint16_t f2bf(float x) {
  uint32_t u = __float_as_uint(x);
  uint32_t r = (u + 0x7FFFu + ((u >> 16) & 1u)) >> 16;
  return (uint16_t)r;
}

// ---------------- elementwise f32 -> bf16 ----------------
__global__ void convert_f32_bf16(const float* __restrict__ in,
                                 uint16_t* __restrict__ out, int n) {
  int i = (blockIdx.x * blockDim.x + threadIdx.x) * 4;
  int stride = gridDim.x * blockDim.x * 4;
  for (; i + 3 < n; i += stride) {
    float4 v = *(const float4*)(in + i);
    ushort4 o;
    o.x = f2bf(v.x); o.y = f2bf(v.y); o.z = f2bf(v.z); o.w = f2bf(v.w);
    *(ushort4*)(out + i) = o;
  }
}

// ---------------- transpose + convert: W [R][C] f32 -> Wt [C][R] bf16 ------
__global__ void transpose_convert(const float* __restrict__ W,
                                  uint16_t* __restrict__ Wt, int R, int C_) {
  __shared__ uint16_t t[64][65];
  int c0 = blockIdx.x * 64, r0 = blockIdx.y * 64;
  int lc = threadIdx.x & 63, lr4 = threadIdx.x >> 6;
#pragma unroll
  for (int rr = 0; rr < 16; ++rr) {
    int r = rr * 4 + lr4;
    t[r][lc] = f2bf(W[(size_t)(r0 + r) * C_ + c0 + lc]);
  }
  __syncthreads();
#pragma unroll
  for (int rr = 0; rr < 16; ++rr) {
    int r = rr * 4 + lr4;  // output row within tile (= source column)
    Wt[(size_t)(c0 + r) * R + r0 + lc] = t[lc][r];
  }
}

// ---------------- V slice of qkv -> Vt [BH][64][T] ----------------
__global__ void transpose_v(const uint16_t* __restrict__ qkv,
                            uint16_t* __restrict__ Vt) {
  __shared__ uint16_t t[64][65];
  int t0 = blockIdx.x * 64;
  int bh = blockIdx.y;
  int b = bh >> 4, h = bh & 15;
  int lc = threadIdx.x & 63, lr4 = threadIdx.x >> 6;
  const uint16_t* src =
      qkv + (size_t)(b * T_SEQ) * (3 * N_EMBD) + 2 * N_EMBD + h * 64;
#pragma unroll
  for (int rr = 0; rr < 16; ++rr) {
    int r = rr * 4 + lr4;  // t index within tile
    t[r][lc] = src[(size_t)(t0 + r) * (3 * N_EMBD) + lc];
  }
  __syncthreads();
  uint16_t* dst = Vt + (size_t)bh * 64 * T_SEQ;
#pragma unroll
  for (int rr = 0; rr < 16; ++rr) {
    int d = rr * 4 + lr4;
    dst[(size_t)d * T_SEQ + t0 + lc] = t[lc][d];
  }
}

// ---------------- GEMM: C[M][N] = A[M][K] * Bt[N][K]^T + bias ----------------
// 128x128 tile, BK=32, 4 waves (2x2), each wave 64x64 = 4x4 mfma 16x16x32 frags.
template <int OUT_BF16>
__global__ __launch_bounds__(256) void gemm_bt(
    const uint16_t* __restrict__ A, const uint16_t* __restrict__ Bt,
    const float* __restrict__ bias, void* __restrict__ Cv, int M, int N,
    int K) {
  __shared__ __attribute__((aligned(16))) uint16_t sA[128 * 32];
  __shared__ __attribute__((aligned(16))) uint16_t sB[128 * 32];
  int tid = threadIdx.x;
  int w = tid >> 6, l = tid & 63;
  int wm = w >> 1, wn = w & 1;
  int ql = l & 15, hi = l >> 4;
  size_t m0 = (size_t)blockIdx.x * 128, n0 = (size_t)blockIdx.y * 128;
  f32x4 acc[4][4] = {};

  for (int kt = 0; kt < K; kt += 32) {
#pragma unroll
    for (int r = 0; r < 2; ++r) {
      int base = r * 256 + (w << 6);  // wave-uniform 16B-unit index
      int idx = base + l;
      gload_lds16(A + (m0 + (idx >> 2)) * K + kt + (idx & 3) * 8, sA + base * 8);
      gload_lds16(Bt + (n0 + (idx >> 2)) * K + kt + (idx & 3) * 8, sB + base * 8);
    }
    __syncthreads();
    bf16x8 af[4], bfr[4];
#pragma unroll
    for (int i = 0; i < 4; i++)
      af[i] = *(const bf16x8*)(sA + (wm * 64 + i * 16 + ql) * 32 + hi * 8);
#pragma unroll
    for (int j = 0; j < 4; j++)
      bfr[j] = *(const bf16x8*)(sB + (wn * 64 + j * 16 + ql) * 32 + hi * 8);
#pragma unroll
    for (int i = 0; i < 4; i++)
#pragma unroll
      for (int j = 0; j < 4; j++)
        acc[i][j] = __builtin_amdgcn_mfma_f32_16x16x32_bf16(af[i], bfr[j],
                                                            acc[i][j], 0, 0, 0);
    __syncthreads();
  }

#pragma unroll
  for (int i = 0; i < 4; i++) {
    size_t m = m0 + wm * 64 + i * 16 + hi * 4;
#pragma unroll
    for (int j = 0; j < 4; j++) {
      size_t n = n0 + wn * 64 + j * 16 + ql;
      float bv = bias[n];
#pragma unroll
      for (int r = 0; r < 4; r++) {
        float v = acc[i][j][r] + bv;
        if (OUT_BF16)
          ((uint16_t*)Cv)[(m + r) * N + n] = f2bf(v);
        else
          ((float*)Cv)[(m + r) * N + n] = v;
      }
    }
  }
}

// ---------------- causal flash attention ----------------
// grid (T/64, B*H), 4 waves/block, each wave owns 16 q-rows. KVBLK=32.
// S^T = mfma(K, Q^T) -> D-layout [key][q]; P bounced via wave-private LDS
// into PV B-frag layout; O^T accumulated via mfma(V^T, P^T).
__global__ __launch_bounds__(256) void attn_kernel(
    const uint16_t* __restrict__ qkv, const uint16_t* __restrict__ Vt,
    uint16_t* __restrict__ y) {
  __shared__ __attribute__((aligned(16))) uint32_t sP[4][16 * 16];
  int tid = threadIdx.x;
  int w = tid >> 6, l = tid & 63;
  int ql = l & 15, hi = l >> 4;
  int bh = blockIdx.y, b = bh >> 4, h = bh & 15;
  int q0 = blockIdx.x * 64 + w * 16;
  const size_t rs = 3 * N_EMBD;
  const uint16_t* Qb = qkv + (size_t)(b * T_SEQ) * rs + h * 64;
  const uint16_t* Kb = Qb + N_EMBD;
  const uint16_t* Vb = Vt + (size_t)bh * 64 * T_SEQ;

  bf16x8 qf0 = *(const bf16x8*)(Qb + (size_t)(q0 + ql) * rs + hi * 8);
  bf16x8 qf1 = *(const bf16x8*)(Qb + (size_t)(q0 + ql) * rs + 32 + hi * 8);

  f32x4 acc[4] = {};
  float m_run = -1e30f, l_run = 0.f;
  const float scale = 0.125f;  // 1/sqrt(64)
  int qg = q0 + ql;

  for (int kv0 = 0; kv0 < q0 + 16; kv0 += 32) {
    f32x4 s0 = {}, s1 = {};
    {
      const uint16_t* K0 = Kb + (size_t)(kv0 + ql) * rs + hi * 8;
      bf16x8 kf;
      kf = *(const bf16x8*)(K0);
      s0 = __builtin_amdgcn_mfma_f32_16x16x32_bf16(kf, qf0, s0, 0, 0, 0);
      kf = *(const bf16x8*)(K0 + 32);
      s0 = __builtin_amdgcn_mfma_f32_16x16x32_bf16(kf, qf1, s0, 0, 0, 0);
      const uint16_t* K1 = K0 + 16 * rs;
      kf = *(const bf16x8*)(K1);
      s1 = __builtin_amdgcn_mfma_f32_16x16x32_bf16(kf, qf0, s1, 0, 0, 0);
      kf = *(const bf16x8*)(K1 + 32);
      s1 = __builtin_amdgcn_mfma_f32_16x16x32_bf16(kf, qf1, s1, 0, 0, 0);
    }
    // scale + causal mask; lane's 8 values all belong to column q = ql
    float sv[8];
#pragma unroll
    for (int f = 0; f < 2; ++f)
#pragma unroll
      for (int r = 0; r < 4; ++r) {
        int kg = kv0 + f * 16 + 4 * hi + r;
        float v = (f ? s1[r] : s0[r]) * scale;
        sv[f * 4 + r] = (kg <= qg) ? v : -1e30f;
      }
    // online softmax (reduce across lanes l, l^16, l^32, l^48)
    float tmax = sv[0];
#pragma unroll
    for (int i = 1; i < 8; i++) tmax = fmaxf(tmax, sv[i]);
    tmax = fmaxf(tmax, __shfl_xor(tmax, 16));
    tmax = fmaxf(tmax, __shfl_xor(tmax, 32));
    float m_new = fmaxf(m_run, tmax);
    float corr = __expf(m_run - m_new);
    float psum = 0.f;
    float pv[8];
#pragma unroll
    for (int i = 0; i < 8; i++) {
      pv[i] = __expf(sv[i] - m_new);
      psum += pv[i];
    }
    psum += __shfl_xor(psum, 16);
    psum += __shfl_xor(psum, 32);
    l_run = l_run * corr + psum;
    m_run = m_new;
#pragma unroll
    for (int d = 0; d < 4; ++d) {
      acc[d][0] *= corr; acc[d][1] *= corr;
      acc[d][2] *= corr; acc[d][3] *= corr;
    }
    // P -> LDS as [q][key] bf16 ([16][32]); key = 16f + 4hi + r
#pragma unroll
    for (int f = 0; f < 2; ++f) {
      uint32_t p01 = (uint32_t)f2bf(pv[f * 4 + 0]) |
                     ((uint32_t)f2bf(pv[f * 4 + 1]) << 16);
      uint32_t p23 = (uint32_t)f2bf(pv[f * 4 + 2]) |
                     ((uint32_t)f2bf(pv[f * 4 + 3]) << 16);
      sP[w][ql * 16 + f * 8 + hi * 2] = p01;
      sP[w][ql * 16 + f * 8 + hi * 2 + 1] = p23;
    }
    // PV B-frag: lane reads P[q=ql][keys 8*hi .. 8*hi+7]
    bf16x8 pf = *(const bf16x8*)((const uint16_t*)&sP[w][0] + ql * 32 + hi * 8);
#pragma unroll
    for (int d = 0; d < 4; ++d) {
      bf16x8 vf =
          *(const bf16x8*)(Vb + (size_t)(d * 16 + ql) * T_SEQ + kv0 + hi * 8);
      acc[d] = __builtin_amdgcn_mfma_f32_16x16x32_bf16(vf, pf, acc[d], 0, 0, 0);
    }
  }

  float inv = 1.0f / l_run;
  uint16_t* yrow = y + (size_t)(b * T_SEQ + qg) * N_EMBD + h * 64;
#pragma unroll
  for (int d = 0; d < 4; ++d) {
    uint32_t o01 = (uint32_t)f2bf(acc[d][0] * inv) |
                   ((uint32_t)f2bf(acc[d][1] * inv) << 16);
    uint32_t o23 = (uint32_t)f2bf(acc[d][2] * inv) |
                   ((uint32_t)f2bf(acc[d][3] * inv) << 16);
    *(uint32_t*)(yrow + d * 16 + hi * 4) = o01;
    *(uint32_t*)(yrow + d * 16 + hi * 4 + 2) = o23;
  }
}

extern "C" void kernel_launch(void* const* d_in, const int* in_sizes, int n_in,
                              void* d_out, int out_size, void* d_ws,
                              size_t ws_size, hipStream_t stream) {
  const float* x = (const float*)d_in[0];
  const float* Wqkv = (const float*)d_in[1];
  const float* bqkv = (const float*)d_in[2];
  const float* Wproj = (const float*)d_in[3];
  const float* bproj = (const float*)d_in[4];
  float* out = (float*)d_out;

  uint8_t* ws = (uint8_t*)d_ws;
  uint16_t* xb = (uint16_t*)(ws);                       //  8 MB: x bf16 [4096][1024]
  uint16_t* wqkvT = (uint16_t*)(ws + (8u << 20));       //  6 MB: Wqkv^T [3072][1024]
  uint16_t* wprojT = (uint16_t*)(ws + (14u << 20));     //  2 MB: Wproj^T [1024][1024]
  uint16_t* qkv = (uint16_t*)(ws + (16u << 20));        // 24 MB: qkv [4096][3072]
  uint16_t* vt = (uint16_t*)(ws + (40u << 20));         //  8 MB: V^T [32][64][2048]
  uint16_t* yb = (uint16_t*)(ws + (48u << 20));         //  8 MB: y [4096][1024]

  convert_f32_bf16<<<dim3(4096), dim3(256), 0, stream>>>(x, xb,
                                                         M_TOK * N_EMBD);
  transpose_convert<<<dim3(3072 / 64, 1024 / 64), dim3(256), 0, stream>>>(
      Wqkv, wqkvT, 1024, 3072);
  transpose_convert<<<dim3(1024 / 64, 1024 / 64), dim3(256), 0, stream>>>(
      Wproj, wprojT, 1024, 1024);
  gemm_bt<1><<<dim3(M_TOK / 128, 3072 / 128), dim3(256), 0, stream>>>(
      xb, wqkvT, bqkv, qkv, M_TOK, 3072, 1024);
  transpose_v<<<dim3(T_SEQ / 64, 32), dim3(256), 0, stream>>>(qkv, vt);
  attn_kernel<<<dim3(T_SEQ / 64, 32), dim3(256), 0, stream>>>(qkv, vt, yb);
  gemm_bt<0><<<dim3(M_TOK / 128, 1024 / 128), dim3(256), 0, stream>>>(
      yb, wprojT, bproj, out, M_TOK, 1024, 1024);
}

// Round 2
// 322.639 us; speedup vs baseline: 1.0002x; 1.0002x over previous
//
#include <hip/hip_runtime.h>
#include <hip/hip_bf16.h>
#include <stdint.h>

#define N_EMBD 1024
#define N_HEAD 16
#define HEAD_DIM 64
#define T_SEQ 2048
#define BATCH 2
#define M_TOK (BATCH * T_SEQ)  // 4096

typedef short bf16x8 __attribute__((ext_vector_type(8)));
typedef float f32x4 __attribute__((ext_vector_type(4)));

__device__ __forceinline__ void gload_lds16(const void* g, void* l) {
  __builtin_amdgcn_global_load_lds(
      (const __attribute__((address_space(1))) void*)g,
      (__attribute__((address_space(3))) void*)l, 16, 0, 0);
}

__device__ __forceinline__ uint16_t f2bf(float x) {
  uint32_t u = __float_as_uint(x);
  uint32_t r = (u + 0x7FFFu + ((u >> 16) & 1u)) >> 16;
  return (uint16_t)r;
}

// ---------------- elementwise f32 -> bf16 ----------------
__global__ void convert_f32_bf16(const float* __restrict__ in,
                                 uint16_t* __restrict__ out, int n) {
  int i = (blockIdx.x * blockDim.x + threadIdx.x) * 4;
  int stride = gridDim.x * blockDim.x * 4;
  for (; i + 3 < n; i += stride) {
    float4 v = *(const float4*)(in + i);
    ushort4 o;
    o.x = f2bf(v.x); o.y = f2bf(v.y); o.z = f2bf(v.z); o.w = f2bf(v.w);
    *(ushort4*)(out + i) = o;
  }
}

// ---------------- transpose + convert: W [R][C] f32 -> Wt [C][R] bf16 ------
__global__ void transpose_convert(const float* __restrict__ W,
                                  uint16_t* __restrict__ Wt, int R, int C_) {
  __shared__ uint16_t t[64][65];
  int c0 = blockIdx.x * 64, r0 = blockIdx.y * 64;
  int lc = threadIdx.x & 63, lr4 = threadIdx.x >> 6;
#pragma unroll
  for (int rr = 0; rr < 16; ++rr) {
    int r = rr * 4 + lr4;
    t[r][lc] = f2bf(W[(size_t)(r0 + r) * C_ + c0 + lc]);
  }
  __syncthreads();
#pragma unroll
  for (int rr = 0; rr < 16; ++rr) {
    int r = rr * 4 + lr4;  // output row within tile (= source column)
    Wt[(size_t)(c0 + r) * R + r0 + lc] = t[lc][r];
  }
}

// ---------------- V slice of qkv -> Vt [BH][64][T] ----------------
__global__ void transpose_v(const uint16_t* __restrict__ qkv,
                            uint16_t* __restrict__ Vt) {
  __shared__ uint16_t t[64][65];
  int t0 = blockIdx.x * 64;
  int bh = blockIdx.y;
  int b = bh >> 4, h = bh & 15;
  int lc = threadIdx.x & 63, lr4 = threadIdx.x >> 6;
  const uint16_t* src =
      qkv + (size_t)(b * T_SEQ) * (3 * N_EMBD) + 2 * N_EMBD + h * 64;
#pragma unroll
  for (int rr = 0; rr < 16; ++rr) {
    int r = rr * 4 + lr4;  // t index within tile
    t[r][lc] = src[(size_t)(t0 + r) * (3 * N_EMBD) + lc];
  }
  __syncthreads();
  uint16_t* dst = Vt + (size_t)bh * 64 * T_SEQ;
#pragma unroll
  for (int rr = 0; rr < 16; ++rr) {
    int d = rr * 4 + lr4;
    dst[(size_t)d * T_SEQ + t0 + lc] = t[lc][d];
  }
}

// ---------------- GEMM: C[M][N] = A[M][K] * Bt[N][K]^T + bias ----------------
// 128x128 tile, BK=32, 4 waves (2x2), each wave 64x64 = 4x4 mfma 16x16x32 frags.
template <int OUT_BF16>
__global__ __launch_bounds__(256) void gemm_bt(
    const uint16_t* __restrict__ A, const uint16_t* __restrict__ Bt,
    const float* __restrict__ bias, void* __restrict__ Cv, int M, int N,
    int K) {
  __shared__ __attribute__((aligned(16))) uint16_t sA[128 * 32];
  __shared__ __attribute__((aligned(16))) uint16_t sB[128 * 32];
  int tid = threadIdx.x;
  int w = tid >> 6, l = tid & 63;
  int wm = w >> 1, wn = w & 1;
  int ql = l & 15, hi = l >> 4;
  size_t m0 = (size_t)blockIdx.x * 128, n0 = (size_t)blockIdx.y * 128;
  f32x4 acc[4][4] = {};

  for (int kt = 0; kt < K; kt += 32) {
#pragma unroll
    for (int r = 0; r < 2; ++r) {
      int base = r * 256 + (w << 6);  // wave-uniform 16B-unit index
      int idx = base + l;
      gload_lds16(A + (m0 + (idx >> 2)) * K + kt + (idx & 3) * 8, sA + base * 8);
      gload_lds16(Bt + (n0 + (idx >> 2)) * K + kt + (idx & 3) * 8, sB + base * 8);
    }
    __syncthreads();
    bf16x8 af[4], bfr[4];
#pragma unroll
    for (int i = 0; i < 4; i++)
      af[i] = *(const bf16x8*)(sA + (wm * 64 + i * 16 + ql) * 32 + hi * 8);
#pragma unroll
    for (int j = 0; j < 4; j++)
      bfr[j] = *(const bf16x8*)(sB + (wn * 64 + j * 16 + ql) * 32 + hi * 8);
#pragma unroll
    for (int i = 0; i < 4; i++)
#pragma unroll
      for (int j = 0; j < 4; j++)
        acc[i][j] = __builtin_amdgcn_mfma_f32_16x16x32_bf16(af[i], bfr[j],
                                                            acc[i][j], 0, 0, 0);
    __syncthreads();
  }

#pragma unroll
  for (int i = 0; i < 4; i++) {
    size_t m = m0 + wm * 64 + i * 16 + hi * 4;
#pragma unroll
    for (int j = 0; j < 4; j++) {
      size_t n = n0 + wn * 64 + j * 16 + ql;
      float bv = bias[n];
#pragma unroll
      for (int r = 0; r < 4; r++) {
        float v = acc[i][j][r] + bv;
        if (OUT_BF16)
          ((uint16_t*)Cv)[(m + r) * N + n] = f2bf(v);
        else
          ((float*)Cv)[(m + r) * N + n] = v;
      }
    }
  }
}

// ---------------- causal flash attention (v2: reg-only P, KVBLK=64) --------
__global__ __launch_bounds__(256) void attn_kernel(
    const uint16_t* __restrict__ qkv, const uint16_t* __restrict__ Vt,
    uint16_t* __restrict__ y) {
  int tid = threadIdx.x;
  int w = tid >> 6, l = tid & 63;
  int ql = l & 15, hi = l >> 4;
  int bh = blockIdx.y, b = bh >> 4, h = bh & 15;
  int qt = gridDim.x - 1 - blockIdx.x;  // heavy tiles first
  int q0 = qt * 64 + w * 16;
  const size_t rs = 3 * N_EMBD;
  const uint16_t* Qb = qkv + (size_t)(b * T_SEQ) * rs + h * 64;
  const uint16_t* Kb = Qb + N_EMBD;
  const uint16_t* Vb = Vt + (size_t)bh * 64 * T_SEQ;

  bf16x8 qf0 = *(const bf16x8*)(Qb + (size_t)(q0 + ql) * rs + hi * 8);
  bf16x8 qf1 = *(const bf16x8*)(Qb + (size_t)(q0 + ql) * rs + 32 + hi * 8);
  // fold scale = 1/8 into Q's bf16 exponent (exact; flush tiny exps to 0)
#pragma unroll
  for (int j = 0; j < 8; ++j) {
    uint16_t u = (uint16_t)qf0[j];
    qf0[j] = (short)(((u & 0x7f80u) >= 0x180u) ? (u - 0x180u) : (u & 0x8000u));
    uint16_t v = (uint16_t)qf1[j];
    qf1[j] = (short)(((v & 0x7f80u) >= 0x180u) ? (v - 0x180u) : (v & 0x8000u));
  }

  f32x4 acc[4] = {};
  float m_run = -1e30f, l_run = 0.f;
  int qg = q0 + ql;
  bool lo = hi < 2;
  int sl0 = ql + ((hi & 1) << 5);
  int sl1 = sl0 + 16;

  for (int kv0 = 0; kv0 < q0 + 16; kv0 += 64) {
    bool full = (kv0 + 32 < q0 + 16);  // wave-uniform
    f32x4 s[4] = {};
    const uint16_t* Kp = Kb + (size_t)(kv0 + ql) * rs + hi * 8;
#pragma unroll
    for (int f = 0; f < 4; ++f) {
      if (f < 2 || full) {
        const uint16_t* kp = Kp + (size_t)f * 16 * rs;
        bf16x8 k0 = *(const bf16x8*)(kp);
        bf16x8 k1 = *(const bf16x8*)(kp + 32);
        s[f] = __builtin_amdgcn_mfma_f32_16x16x32_bf16(k0, qf0, s[f], 0, 0, 0);
        s[f] = __builtin_amdgcn_mfma_f32_16x16x32_bf16(k1, qf1, s[f], 0, 0, 0);
      }
    }
    // V loads issued early (hide L2 latency under softmax)
    bf16x8 vf0[4], vf1[4];
#pragma unroll
    for (int d = 0; d < 4; ++d) {
      const uint16_t* vp = Vb + (size_t)(d * 16 + ql) * T_SEQ + kv0 + hi * 8;
      vf0[d] = *(const bf16x8*)(vp);
      if (full) vf1[d] = *(const bf16x8*)(vp + 32);
    }
    float sv[16];
#pragma unroll
    for (int f = 0; f < 4; ++f)
#pragma unroll
      for (int r = 0; r < 4; ++r) {
        int kg = kv0 + f * 16 + 4 * hi + r;
        sv[f * 4 + r] = (kg <= qg) ? s[f][r] : -1e30f;
      }
    float t0 = fmaxf(fmaxf(sv[0], sv[1]), fmaxf(sv[2], sv[3]));
    float t1 = fmaxf(fmaxf(sv[4], sv[5]), fmaxf(sv[6], sv[7]));
    float t2 = fmaxf(fmaxf(sv[8], sv[9]), fmaxf(sv[10], sv[11]));
    float t3 = fmaxf(fmaxf(sv[12], sv[13]), fmaxf(sv[14], sv[15]));
    float tmax = fmaxf(fmaxf(t0, t1), fmaxf(t2, t3));
    tmax = fmaxf(tmax, __shfl_xor(tmax, 16));
    tmax = fmaxf(tmax, __shfl_xor(tmax, 32));
    float m_new = fmaxf(m_run, tmax);
    float corr = __expf(m_run - m_new);
    float pv[16];
    float ps0 = 0.f, ps1 = 0.f;
#pragma unroll
    for (int i = 0; i < 16; i += 2) {
      pv[i] = __expf(sv[i] - m_new);
      pv[i + 1] = __expf(sv[i + 1] - m_new);
      ps0 += pv[i];
      ps1 += pv[i + 1];
    }
    float psum = ps0 + ps1;
    psum += __shfl_xor(psum, 16);
    psum += __shfl_xor(psum, 32);
    l_run = l_run * corr + psum;
    m_run = m_new;
#pragma unroll
    for (int d = 0; d < 4; ++d) {
      acc[d][0] *= corr; acc[d][1] *= corr;
      acc[d][2] *= corr; acc[d][3] *= corr;
    }
    uint32_t wp[8];
#pragma unroll
    for (int f = 0; f < 4; ++f) {
      wp[2 * f] = (uint32_t)f2bf(pv[4 * f]) | ((uint32_t)f2bf(pv[4 * f + 1]) << 16);
      wp[2 * f + 1] =
          (uint32_t)f2bf(pv[4 * f + 2]) | ((uint32_t)f2bf(pv[4 * f + 3]) << 16);
    }
    union { uint32_t u[4]; bf16x8 v; } pf0, pf1;
    {
      uint32_t a0 = __shfl((int)wp[0], sl0), b0 = __shfl((int)wp[2], sl0);
      uint32_t a1 = __shfl((int)wp[1], sl0), b1 = __shfl((int)wp[3], sl0);
      uint32_t a2 = __shfl((int)wp[0], sl1), b2 = __shfl((int)wp[2], sl1);
      uint32_t a3 = __shfl((int)wp[1], sl1), b3 = __shfl((int)wp[3], sl1);
      pf0.u[0] = lo ? a0 : b0; pf0.u[1] = lo ? a1 : b1;
      pf0.u[2] = lo ? a2 : b2; pf0.u[3] = lo ? a3 : b3;
    }
#pragma unroll
    for (int d = 0; d < 4; ++d)
      acc[d] =
          __builtin_amdgcn_mfma_f32_16x16x32_bf16(vf0[d], pf0.v, acc[d], 0, 0, 0);
    if (full) {
      uint32_t a0 = __shfl((int)wp[4], sl0), b0 = __shfl((int)wp[6], sl0);
      uint32_t a1 = __shfl((int)wp[5], sl0), b1 = __shfl((int)wp[7], sl0);
      uint32_t a2 = __shfl((int)wp[4], sl1), b2 = __shfl((int)wp[6], sl1);
      uint32_t a3 = __shfl((int)wp[5], sl1), b3 = __shfl((int)wp[7], sl1);
      pf1.u[0] = lo ? a0 : b0; pf1.u[1] = lo ? a1 : b1;
      pf1.u[2] = lo ? a2 : b2; pf1.u[3] = lo ? a3 : b3;
#pragma unroll
      for (int d = 0; d < 4; ++d)
        acc[d] = __builtin_amdgcn_mfma_f32_16x16x32_bf16(vf1[d], pf1.v, acc[d],
                                                         0, 0, 0);
    }
  }

  float inv = 1.0f / l_run;
  uint16_t* yrow = y + (size_t)(b * T_SEQ + qg) * N_EMBD + h * 64;
#pragma unroll
  for (int d = 0; d < 4; ++d) {
    uint32_t o01 = (uint32_t)f2bf(acc[d][0] * inv) |
                   ((uint32_t)f2bf(acc[d][1] * inv) << 16);
    uint32_t o23 = (uint32_t)f2bf(acc[d][2] * inv) |
                   ((uint32_t)f2bf(acc[d][3] * inv) << 16);
    *(uint32_t*)(yrow + d * 16 + hi * 4) = o01;
    *(uint32_t*)(yrow + d * 16 + hi * 4 + 2) = o23;
  }
}

extern "C" void kernel_launch(void* const* d_in, const int* in_sizes, int n_in,
                              void* d_out, int out_size, void* d_ws,
                              size_t ws_size, hipStream_t stream) {
  const float* x = (const float*)d_in[0];
  const float* Wqkv = (const float*)d_in[1];
  const float* bqkv = (const float*)d_in[2];
  const float* Wproj = (const float*)d_in[3];
  const float* bproj = (const float*)d_in[4];
  float* out = (float*)d_out;

  uint8_t* ws = (uint8_t*)d_ws;
  uint16_t* xb = (uint16_t*)(ws);                       //  8 MB: x bf16 [4096][1024]
  uint16_t* wqkvT = (uint16_t*)(ws + (8u << 20));       //  6 MB: Wqkv^T [3072][1024]
  uint16_t* wprojT = (uint16_t*)(ws + (14u << 20));     //  2 MB: Wproj^T [1024][1024]
  uint16_t* qkv = (uint16_t*)(ws + (16u << 20));        // 24 MB: qkv [4096][3072]
  uint16_t* vt = (uint16_t*)(ws + (40u << 20));         //  8 MB: V^T [32][64][2048]
  uint16_t* yb = (uint16_t*)(ws + (48u << 20));         //  8 MB: y [4096][1024]

  convert_f32_bf16<<<dim3(4096), dim3(256), 0, stream>>>(x, xb,
                                                         M_TOK * N_EMBD);
  transpose_convert<<<dim3(3072 / 64, 1024 / 64), dim3(256), 0, stream>>>(
      Wqkv, wqkvT, 1024, 3072);
  transpose_convert<<<dim3(1024 / 64, 1024 / 64), dim3(256), 0, stream>>>(
      Wproj, wprojT, 1024, 1024);
  gemm_bt<1><<<dim3(M_TOK / 128, 3072 / 128), dim3(256), 0, stream>>>(
      xb, wqkvT, bqkv, qkv, M_TOK, 3072, 1024);
  transpose_v<<<dim3(T_SEQ / 64, 32), dim3(256), 0, stream>>>(qkv, vt);
  attn_kernel<<<dim3(T_SEQ / 64, 32), dim3(256), 0, stream>>>(qkv, vt, yb);
  gemm_bt<0><<<dim3(M_TOK / 128, 1024 / 128), dim3(256), 0, stream>>>(
      yb, wprojT, bproj, out, M_TOK, 1024, 1024);
}

// Round 3
// 214.472 us; speedup vs baseline: 1.5047x; 1.5043x over previous
//
#include <hip/hip_runtime.h>
#include <hip/hip_bf16.h>
#include <stdint.h>

#define N_EMBD 1024
#define N_HEAD 16
#define HEAD_DIM 64
#define T_SEQ 2048
#define BATCH 2
#define M_TOK (BATCH * T_SEQ)  // 4096

typedef short bf16x8 __attribute__((ext_vector_type(8)));
typedef float f32x4 __attribute__((ext_vector_type(4)));

__device__ __forceinline__ void gload_lds16(const void* g, void* l) {
  __builtin_amdgcn_global_load_lds(
      (const __attribute__((address_space(1))) void*)g,
      (__attribute__((address_space(3))) void*)l, 16, 0, 0);
}

__device__ __forceinline__ uint16_t f2bf(float x) {
  uint32_t u = __float_as_uint(x);
  uint32_t r = (u + 0x7FFFu + ((u >> 16) & 1u)) >> 16;
  return (uint16_t)r;
}

// ---------------- elementwise f32 -> bf16 ----------------
__global__ void convert_f32_bf16(const float* __restrict__ in,
                                 uint16_t* __restrict__ out, int n) {
  int i = (blockIdx.x * blockDim.x + threadIdx.x) * 4;
  int stride = gridDim.x * blockDim.x * 4;
  for (; i + 3 < n; i += stride) {
    float4 v = *(const float4*)(in + i);
    ushort4 o;
    o.x = f2bf(v.x); o.y = f2bf(v.y); o.z = f2bf(v.z); o.w = f2bf(v.w);
    *(ushort4*)(out + i) = o;
  }
}

// ---------------- transpose + convert: W [R][C] f32 -> Wt [C][R] bf16 ------
__global__ void transpose_convert(const float* __restrict__ W,
                                  uint16_t* __restrict__ Wt, int R, int C_) {
  __shared__ uint16_t t[64][65];
  int c0 = blockIdx.x * 64, r0 = blockIdx.y * 64;
  int lc = threadIdx.x & 63, lr4 = threadIdx.x >> 6;
#pragma unroll
  for (int rr = 0; rr < 16; ++rr) {
    int r = rr * 4 + lr4;
    t[r][lc] = f2bf(W[(size_t)(r0 + r) * C_ + c0 + lc]);
  }
  __syncthreads();
#pragma unroll
  for (int rr = 0; rr < 16; ++rr) {
    int r = rr * 4 + lr4;  // output row within tile (= source column)
    Wt[(size_t)(c0 + r) * R + r0 + lc] = t[lc][r];
  }
}

// ---------------- V slice of qkv -> Vt [BH][64][T] ----------------
__global__ void transpose_v(const uint16_t* __restrict__ qkv,
                            uint16_t* __restrict__ Vt) {
  __shared__ uint16_t t[64][65];
  int t0 = blockIdx.x * 64;
  int bh = blockIdx.y;
  int b = bh >> 4, h = bh & 15;
  int lc = threadIdx.x & 63, lr4 = threadIdx.x >> 6;
  const uint16_t* src =
      qkv + (size_t)(b * T_SEQ) * (3 * N_EMBD) + 2 * N_EMBD + h * 64;
#pragma unroll
  for (int rr = 0; rr < 16; ++rr) {
    int r = rr * 4 + lr4;  // t index within tile
    t[r][lc] = src[(size_t)(t0 + r) * (3 * N_EMBD) + lc];
  }
  __syncthreads();
  uint16_t* dst = Vt + (size_t)bh * 64 * T_SEQ;
#pragma unroll
  for (int rr = 0; rr < 16; ++rr) {
    int d = rr * 4 + lr4;
    dst[(size_t)d * T_SEQ + t0 + lc] = t[lc][d];
  }
}

// ---------------- GEMM: C[M][N] = A[M][K] * Bt[N][K]^T + bias ----------------
template <int OUT_BF16>
__global__ __launch_bounds__(256) void gemm_bt(
    const uint16_t* __restrict__ A, const uint16_t* __restrict__ Bt,
    const float* __restrict__ bias, void* __restrict__ Cv, int M, int N,
    int K) {
  __shared__ __attribute__((aligned(16))) uint16_t sA[128 * 32];
  __shared__ __attribute__((aligned(16))) uint16_t sB[128 * 32];
  int tid = threadIdx.x;
  int w = tid >> 6, l = tid & 63;
  int wm = w >> 1, wn = w & 1;
  int ql = l & 15, hi = l >> 4;
  size_t m0 = (size_t)blockIdx.x * 128, n0 = (size_t)blockIdx.y * 128;
  f32x4 acc[4][4] = {};

  for (int kt = 0; kt < K; kt += 32) {
#pragma unroll
    for (int r = 0; r < 2; ++r) {
      int base = r * 256 + (w << 6);  // wave-uniform 16B-unit index
      int idx = base + l;
      gload_lds16(A + (m0 + (idx >> 2)) * K + kt + (idx & 3) * 8, sA + base * 8);
      gload_lds16(Bt + (n0 + (idx >> 2)) * K + kt + (idx & 3) * 8, sB + base * 8);
    }
    __syncthreads();
    bf16x8 af[4], bfr[4];
#pragma unroll
    for (int i = 0; i < 4; i++)
      af[i] = *(const bf16x8*)(sA + (wm * 64 + i * 16 + ql) * 32 + hi * 8);
#pragma unroll
    for (int j = 0; j < 4; j++)
      bfr[j] = *(const bf16x8*)(sB + (wn * 64 + j * 16 + ql) * 32 + hi * 8);
#pragma unroll
    for (int i = 0; i < 4; i++)
#pragma unroll
      for (int j = 0; j < 4; j++)
        acc[i][j] = __builtin_amdgcn_mfma_f32_16x16x32_bf16(af[i], bfr[j],
                                                            acc[i][j], 0, 0, 0);
    __syncthreads();
  }

#pragma unroll
  for (int i = 0; i < 4; i++) {
    size_t m = m0 + wm * 64 + i * 16 + hi * 4;
#pragma unroll
    for (int j = 0; j < 4; j++) {
      size_t n = n0 + wn * 64 + j * 16 + ql;
      float bv = bias[n];
#pragma unroll
      for (int r = 0; r < 4; r++) {
        float v = acc[i][j][r] + bv;
        if (OUT_BF16)
          ((uint16_t*)Cv)[(m + r) * N + n] = f2bf(v);
        else
          ((float*)Cv)[(m + r) * N + n] = v;
      }
    }
  }
}

// ---------------- causal flash attention (v3) ------------------------------
// Wave-uniform work: each wave processes 16-row strips s and 127-s
// sequentially (33 K-tile iterations total, identical for every wave).
// K software-pipelined in registers; V issued early; defer-max softmax;
// cvt_pk bf16 packing; reg-only P redistribute (shfl).
__device__ __forceinline__ void attn_strip(
    const uint16_t* __restrict__ Qb, const uint16_t* __restrict__ Kb,
    const uint16_t* __restrict__ Vb, uint16_t* __restrict__ y, int b, int h,
    int q0, int ql, int hi, bool lo, int sl0, int sl1) {
  const size_t rs = 3 * N_EMBD;
  const int qg = q0 + ql;
  bf16x8 qf0 = *(const bf16x8*)(Qb + (size_t)qg * rs + hi * 8);
  bf16x8 qf1 = *(const bf16x8*)(Qb + (size_t)qg * rs + 32 + hi * 8);
  // fold scale = 1/8 into Q's bf16 exponent (exact; flush tiny exps to 0)
#pragma unroll
  for (int j = 0; j < 8; ++j) {
    uint16_t u = (uint16_t)qf0[j];
    qf0[j] = (short)(((u & 0x7f80u) >= 0x180u) ? (u - 0x180u) : (u & 0x8000u));
    uint16_t v = (uint16_t)qf1[j];
    qf1[j] = (short)(((v & 0x7f80u) >= 0x180u) ? (v - 0x180u) : (v & 0x8000u));
  }
  f32x4 acc[4] = {};
  float m_run = -1e30f, l_part = 0.f;
  const int nIter = (q0 + 79) >> 6;  // ceil((q0+16)/64)
  const uint16_t* kptr = Kb + (size_t)ql * rs + hi * 8;
  const uint16_t* vptr = Vb + (size_t)ql * T_SEQ + hi * 8;
  bf16x8 kr[8];
#pragma unroll
  for (int f = 0; f < 4; ++f) {
    kr[2 * f] = *(const bf16x8*)(kptr + (size_t)(16 * f) * rs);
    kr[2 * f + 1] = *(const bf16x8*)(kptr + (size_t)(16 * f) * rs + 32);
  }
  for (int it = 0; it < nIter; ++it) {
    const int kv0 = it << 6;
    // V loads early: consumed ~softmax-duration later
    bf16x8 vf[8];
#pragma unroll
    for (int d = 0; d < 4; ++d) {
      vf[2 * d] = *(const bf16x8*)(vptr + (size_t)(16 * d) * T_SEQ + kv0);
      vf[2 * d + 1] =
          *(const bf16x8*)(vptr + (size_t)(16 * d) * T_SEQ + kv0 + 32);
    }
    // QK^T (consumes kr loaded last iteration)
    f32x4 s[4] = {};
    __builtin_amdgcn_s_setprio(1);
#pragma unroll
    for (int f = 0; f < 4; ++f) {
      s[f] = __builtin_amdgcn_mfma_f32_16x16x32_bf16(kr[2 * f], qf0, s[f], 0, 0, 0);
      s[f] =
          __builtin_amdgcn_mfma_f32_16x16x32_bf16(kr[2 * f + 1], qf1, s[f], 0, 0, 0);
    }
    __builtin_amdgcn_s_setprio(0);
    // prefetch next K tile into just-freed kr (hidden under softmax+PV)
    if (it + 1 < nIter) {
      const uint16_t* knext = kptr + (size_t)(kv0 + 64) * rs;
#pragma unroll
      for (int f = 0; f < 4; ++f) {
        kr[2 * f] = *(const bf16x8*)(knext + (size_t)(16 * f) * rs);
        kr[2 * f + 1] = *(const bf16x8*)(knext + (size_t)(16 * f) * rs + 32);
      }
    }
    // mask only on the final iteration (provably unmasked before)
    float sv[16];
    if (it == nIter - 1) {
      const int kb = kv0 + 4 * hi;
#pragma unroll
      for (int f = 0; f < 4; ++f)
#pragma unroll
        for (int r = 0; r < 4; ++r)
          sv[4 * f + r] = (kb + 16 * f + r <= qg) ? s[f][r] : -1e30f;
    } else {
#pragma unroll
      for (int f = 0; f < 4; ++f)
#pragma unroll
        for (int r = 0; r < 4; ++r) sv[4 * f + r] = s[f][r];
    }
    // in-lane max, defer-max: rescale only when some lane's max grew
    float m0 = fmaxf(fmaxf(sv[0], sv[1]), fmaxf(sv[2], sv[3]));
    float m1 = fmaxf(fmaxf(sv[4], sv[5]), fmaxf(sv[6], sv[7]));
    float m2 = fmaxf(fmaxf(sv[8], sv[9]), fmaxf(sv[10], sv[11]));
    float m3 = fmaxf(fmaxf(sv[12], sv[13]), fmaxf(sv[14], sv[15]));
    float tmax = fmaxf(fmaxf(m0, m1), fmaxf(m2, m3));
    if (__any(tmax > m_run)) {
      float tm = fmaxf(tmax, __shfl_xor(tmax, 16));
      tm = fmaxf(tm, __shfl_xor(tm, 32));
      float m_new = fmaxf(m_run, tm);
      float corr = __expf(m_run - m_new);
      m_run = m_new;
      l_part *= corr;
#pragma unroll
      for (int d = 0; d < 4; ++d) acc[d] *= corr;
    }
    float pv[16];
#pragma unroll
    for (int i2 = 0; i2 < 16; ++i2) pv[i2] = __expf(sv[i2] - m_run);
    float s01 = (pv[0] + pv[1]) + (pv[2] + pv[3]);
    float s23 = (pv[4] + pv[5]) + (pv[6] + pv[7]);
    float s45 = (pv[8] + pv[9]) + (pv[10] + pv[11]);
    float s67 = (pv[12] + pv[13]) + (pv[14] + pv[15]);
    l_part += (s01 + s23) + (s45 + s67);
    // pack P to bf16 pairs (keys 16f+4hi+{0,1} / {2,3})
    uint32_t wp[8];
#pragma unroll
    for (int f = 0; f < 4; ++f) {
      asm("v_cvt_pk_bf16_f32 %0, %1, %2"
          : "=v"(wp[2 * f]) : "v"(pv[4 * f]), "v"(pv[4 * f + 1]));
      asm("v_cvt_pk_bf16_f32 %0, %1, %2"
          : "=v"(wp[2 * f + 1]) : "v"(pv[4 * f + 2]), "v"(pv[4 * f + 3]));
    }
    // redistribute to PV B-frag (lane gets keys 8hi..8hi+7)
    union { uint32_t u[4]; bf16x8 v; } pf0, pf1;
    {
      uint32_t a0 = __shfl((int)wp[0], sl0), b0 = __shfl((int)wp[2], sl0);
      uint32_t a1 = __shfl((int)wp[1], sl0), b1 = __shfl((int)wp[3], sl0);
      uint32_t a2 = __shfl((int)wp[0], sl1), b2 = __shfl((int)wp[2], sl1);
      uint32_t a3 = __shfl((int)wp[1], sl1), b3 = __shfl((int)wp[3], sl1);
      pf0.u[0] = lo ? a0 : b0; pf0.u[1] = lo ? a1 : b1;
      pf0.u[2] = lo ? a2 : b2; pf0.u[3] = lo ? a3 : b3;
    }
    {
      uint32_t a0 = __shfl((int)wp[4], sl0), b0 = __shfl((int)wp[6], sl0);
      uint32_t a1 = __shfl((int)wp[5], sl0), b1 = __shfl((int)wp[7], sl0);
      uint32_t a2 = __shfl((int)wp[4], sl1), b2 = __shfl((int)wp[6], sl1);
      uint32_t a3 = __shfl((int)wp[5], sl1), b3 = __shfl((int)wp[7], sl1);
      pf1.u[0] = lo ? a0 : b0; pf1.u[1] = lo ? a1 : b1;
      pf1.u[2] = lo ? a2 : b2; pf1.u[3] = lo ? a3 : b3;
    }
    // PV: O^T += V^T * P^T
    __builtin_amdgcn_s_setprio(1);
#pragma unroll
    for (int d = 0; d < 4; ++d)
      acc[d] =
          __builtin_amdgcn_mfma_f32_16x16x32_bf16(vf[2 * d], pf0.v, acc[d], 0, 0, 0);
#pragma unroll
    for (int d = 0; d < 4; ++d)
      acc[d] = __builtin_amdgcn_mfma_f32_16x16x32_bf16(vf[2 * d + 1], pf1.v,
                                                       acc[d], 0, 0, 0);
    __builtin_amdgcn_s_setprio(0);
  }
  float lt = l_part + __shfl_xor(l_part, 16);
  lt += __shfl_xor(lt, 32);
  float inv = 1.0f / lt;
  uint16_t* yrow = y + (size_t)(b * T_SEQ + qg) * N_EMBD + h * 64;
#pragma unroll
  for (int d = 0; d < 4; ++d) {
    uint32_t o01, o23;
    float v0 = acc[d][0] * inv, v1 = acc[d][1] * inv;
    float v2 = acc[d][2] * inv, v3 = acc[d][3] * inv;
    asm("v_cvt_pk_bf16_f32 %0, %1, %2" : "=v"(o01) : "v"(v0), "v"(v1));
    asm("v_cvt_pk_bf16_f32 %0, %1, %2" : "=v"(o23) : "v"(v2), "v"(v3));
    *(uint32_t*)(yrow + d * 16 + hi * 4) = o01;
    *(uint32_t*)(yrow + d * 16 + hi * 4 + 2) = o23;
  }
}

__global__ __launch_bounds__(256) void attn_kernel(
    const uint16_t* __restrict__ qkv, const uint16_t* __restrict__ Vt,
    uint16_t* __restrict__ y) {
  int tid = threadIdx.x;
  int w = tid >> 6, l = tid & 63;
  int ql = l & 15, hi = l >> 4;
  int bh = blockIdx.y, b = bh >> 4, h = bh & 15;
  int sA = blockIdx.x * 4 + w;         // 0..63
  int q0A = sA * 16;
  int q0B = (127 - sA) * 16;           // complement strip: uniform total work
  const size_t rs = 3 * N_EMBD;
  const uint16_t* Qb = qkv + (size_t)(b * T_SEQ) * rs + h * 64;
  const uint16_t* Kb = Qb + N_EMBD;
  const uint16_t* Vb = Vt + (size_t)bh * 64 * T_SEQ;
  bool lo = hi < 2;
  int sl0 = ql + ((hi & 1) << 5);
  int sl1 = sl0 + 16;
  attn_strip(Qb, Kb, Vb, y, b, h, q0A, ql, hi, lo, sl0, sl1);
  attn_strip(Qb, Kb, Vb, y, b, h, q0B, ql, hi, lo, sl0, sl1);
}

extern "C" void kernel_launch(void* const* d_in, const int* in_sizes, int n_in,
                              void* d_out, int out_size, void* d_ws,
                              size_t ws_size, hipStream_t stream) {
  const float* x = (const float*)d_in[0];
  const float* Wqkv = (const float*)d_in[1];
  const float* bqkv = (const float*)d_in[2];
  const float* Wproj = (const float*)d_in[3];
  const float* bproj = (const float*)d_in[4];
  float* out = (float*)d_out;

  uint8_t* ws = (uint8_t*)d_ws;
  uint16_t* xb = (uint16_t*)(ws);                       //  8 MB: x bf16 [4096][1024]
  uint16_t* wqkvT = (uint16_t*)(ws + (8u << 20));       //  6 MB: Wqkv^T [3072][1024]
  uint16_t* wprojT = (uint16_t*)(ws + (14u << 20));     //  2 MB: Wproj^T [1024][1024]
  uint16_t* qkv = (uint16_t*)(ws + (16u << 20));        // 24 MB: qkv [4096][3072]
  uint16_t* vt = (uint16_t*)(ws + (40u << 20));         //  8 MB: V^T [32][64][2048]
  uint16_t* yb = (uint16_t*)(ws + (48u << 20));         //  8 MB: y [4096][1024]

  convert_f32_bf16<<<dim3(4096), dim3(256), 0, stream>>>(x, xb,
                                                         M_TOK * N_EMBD);
  transpose_convert<<<dim3(3072 / 64, 1024 / 64), dim3(256), 0, stream>>>(
      Wqkv, wqkvT, 1024, 3072);
  transpose_convert<<<dim3(1024 / 64, 1024 / 64), dim3(256), 0, stream>>>(
      Wproj, wprojT, 1024, 1024);
  gemm_bt<1><<<dim3(M_TOK / 128, 3072 / 128), dim3(256), 0, stream>>>(
      xb, wqkvT, bqkv, qkv, M_TOK, 3072, 1024);
  transpose_v<<<dim3(T_SEQ / 64, 32), dim3(256), 0, stream>>>(qkv, vt);
  attn_kernel<<<dim3(T_SEQ / 128, 32), dim3(256), 0, stream>>>(qkv, vt, yb);
  gemm_bt<0><<<dim3(M_TOK / 128, 1024 / 128), dim3(256), 0, stream>>>(
      yb, wprojT, bproj, out, M_TOK, 1024, 1024);
}

// Round 4
// 214.415 us; speedup vs baseline: 1.5051x; 1.0003x over previous
//
#include <hip/hip_runtime.h>
#include <hip/hip_bf16.h>
#include <stdint.h>

#define N_EMBD 1024
#define N_HEAD 16
#define HEAD_DIM 64
#define T_SEQ 2048
#define BATCH 2
#define M_TOK (BATCH * T_SEQ)  // 4096

typedef short bf16x8 __attribute__((ext_vector_type(8)));
typedef float f32x4 __attribute__((ext_vector_type(4)));

__device__ __forceinline__ void gload_lds16(const void* g, void* l) {
  __builtin_amdgcn_global_load_lds(
      (const __attribute__((address_space(1))) void*)g,
      (__attribute__((address_space(3))) void*)l, 16, 0, 0);
}

__device__ __forceinline__ uint16_t f2bf(float x) {
  uint32_t u = __float_as_uint(x);
  uint32_t r = (u + 0x7FFFu + ((u >> 16) & 1u)) >> 16;
  return (uint16_t)r;
}

// ---------------- elementwise f32 -> bf16 ----------------
__global__ void convert_f32_bf16(const float* __restrict__ in,
                                 uint16_t* __restrict__ out, int n) {
  int i = (blockIdx.x * blockDim.x + threadIdx.x) * 4;
  int stride = gridDim.x * blockDim.x * 4;
  for (; i + 3 < n; i += stride) {
    float4 v = *(const float4*)(in + i);
    ushort4 o;
    o.x = f2bf(v.x); o.y = f2bf(v.y); o.z = f2bf(v.z); o.w = f2bf(v.w);
    *(ushort4*)(out + i) = o;
  }
}

// ---------------- transpose + convert: W [R][C] f32 -> Wt [C][R] bf16 ------
__global__ void transpose_convert(const float* __restrict__ W,
                                  uint16_t* __restrict__ Wt, int R, int C_) {
  __shared__ uint16_t t[64][65];
  int c0 = blockIdx.x * 64, r0 = blockIdx.y * 64;
  int lc = threadIdx.x & 63, lr4 = threadIdx.x >> 6;
#pragma unroll
  for (int rr = 0; rr < 16; ++rr) {
    int r = rr * 4 + lr4;
    t[r][lc] = f2bf(W[(size_t)(r0 + r) * C_ + c0 + lc]);
  }
  __syncthreads();
#pragma unroll
  for (int rr = 0; rr < 16; ++rr) {
    int r = rr * 4 + lr4;  // output row within tile (= source column)
    Wt[(size_t)(c0 + r) * R + r0 + lc] = t[lc][r];
  }
}

// ---------------- V slice of qkv -> Vt [BH][64][T] ----------------
__global__ void transpose_v(const uint16_t* __restrict__ qkv,
                            uint16_t* __restrict__ Vt) {
  __shared__ uint16_t t[64][65];
  int t0 = blockIdx.x * 64;
  int bh = blockIdx.y;
  int b = bh >> 4, h = bh & 15;
  int lc = threadIdx.x & 63, lr4 = threadIdx.x >> 6;
  const uint16_t* src =
      qkv + (size_t)(b * T_SEQ) * (3 * N_EMBD) + 2 * N_EMBD + h * 64;
#pragma unroll
  for (int rr = 0; rr < 16; ++rr) {
    int r = rr * 4 + lr4;  // t index within tile
    t[r][lc] = src[(size_t)(t0 + r) * (3 * N_EMBD) + lc];
  }
  __syncthreads();
  uint16_t* dst = Vt + (size_t)bh * 64 * T_SEQ;
#pragma unroll
  for (int rr = 0; rr < 16; ++rr) {
    int d = rr * 4 + lr4;
    dst[(size_t)d * T_SEQ + t0 + lc] = t[lc][d];
  }
}

// ---------------- GEMM: C[M][N] = A[M][K] * Bt[N][K]^T + bias ----------------
template <int OUT_BF16>
__global__ __launch_bounds__(256) void gemm_bt(
    const uint16_t* __restrict__ A, const uint16_t* __restrict__ Bt,
    const float* __restrict__ bias, void* __restrict__ Cv, int M, int N,
    int K) {
  __shared__ __attribute__((aligned(16))) uint16_t sA[128 * 32];
  __shared__ __attribute__((aligned(16))) uint16_t sB[128 * 32];
  int tid = threadIdx.x;
  int w = tid >> 6, l = tid & 63;
  int wm = w >> 1, wn = w & 1;
  int ql = l & 15, hi = l >> 4;
  size_t m0 = (size_t)blockIdx.x * 128, n0 = (size_t)blockIdx.y * 128;
  f32x4 acc[4][4] = {};

  for (int kt = 0; kt < K; kt += 32) {
#pragma unroll
    for (int r = 0; r < 2; ++r) {
      int base = r * 256 + (w << 6);  // wave-uniform 16B-unit index
      int idx = base + l;
      gload_lds16(A + (m0 + (idx >> 2)) * K + kt + (idx & 3) * 8, sA + base * 8);
      gload_lds16(Bt + (n0 + (idx >> 2)) * K + kt + (idx & 3) * 8, sB + base * 8);
    }
    __syncthreads();
    bf16x8 af[4], bfr[4];
#pragma unroll
    for (int i = 0; i < 4; i++)
      af[i] = *(const bf16x8*)(sA + (wm * 64 + i * 16 + ql) * 32 + hi * 8);
#pragma unroll
    for (int j = 0; j < 4; j++)
      bfr[j] = *(const bf16x8*)(sB + (wn * 64 + j * 16 + ql) * 32 + hi * 8);
#pragma unroll
    for (int i = 0; i < 4; i++)
#pragma unroll
      for (int j = 0; j < 4; j++)
        acc[i][j] = __builtin_amdgcn_mfma_f32_16x16x32_bf16(af[i], bfr[j],
                                                            acc[i][j], 0, 0, 0);
    __syncthreads();
  }

#pragma unroll
  for (int i = 0; i < 4; i++) {
    size_t m = m0 + wm * 64 + i * 16 + hi * 4;
#pragma unroll
    for (int j = 0; j < 4; j++) {
      size_t n = n0 + wn * 64 + j * 16 + ql;
      float bv = bias[n];
#pragma unroll
      for (int r = 0; r < 4; r++) {
        float v = acc[i][j][r] + bv;
        if (OUT_BF16)
          ((uint16_t*)Cv)[(m + r) * N + n] = f2bf(v);
        else
          ((float*)Cv)[(m + r) * N + n] = v;
      }
    }
  }
}

// ---------------- causal flash attention (v4: XCD-local bh) ----------------
// Each XCD owns 4 bh values -> K/V working set 2 MB fits its 4 MB L2.
// Wave-uniform work via complement strip pairing (33 iters/wave).
__device__ __forceinline__ void attn_strip(
    const uint16_t* __restrict__ Qb, const uint16_t* __restrict__ Kb,
    const uint16_t* __restrict__ Vb, uint16_t* __restrict__ y, int b, int h,
    int q0, int ql, int hi, bool lo, int sl0, int sl1) {
  const size_t rs = 3 * N_EMBD;
  const int qg = q0 + ql;
  bf16x8 qf0 = *(const bf16x8*)(Qb + (size_t)qg * rs + hi * 8);
  bf16x8 qf1 = *(const bf16x8*)(Qb + (size_t)qg * rs + 32 + hi * 8);
  // fold scale = 1/8 into Q's bf16 exponent (exact; flush tiny exps to 0)
#pragma unroll
  for (int j = 0; j < 8; ++j) {
    uint16_t u = (uint16_t)qf0[j];
    qf0[j] = (short)(((u & 0x7f80u) >= 0x180u) ? (u - 0x180u) : (u & 0x8000u));
    uint16_t v = (uint16_t)qf1[j];
    qf1[j] = (short)(((v & 0x7f80u) >= 0x180u) ? (v - 0x180u) : (v & 0x8000u));
  }
  f32x4 acc[4] = {};
  float m_run = -1e30f, l_part = 0.f;
  const int nIter = (q0 + 79) >> 6;  // ceil((q0+16)/64)
  const uint16_t* kptr = Kb + (size_t)ql * rs + hi * 8;
  const uint16_t* vptr = Vb + (size_t)ql * T_SEQ + hi * 8;
  bf16x8 kr[8];
#pragma unroll
  for (int f = 0; f < 4; ++f) {
    kr[2 * f] = *(const bf16x8*)(kptr + (size_t)(16 * f) * rs);
    kr[2 * f + 1] = *(const bf16x8*)(kptr + (size_t)(16 * f) * rs + 32);
  }
  for (int it = 0; it < nIter; ++it) {
    const int kv0 = it << 6;
    // V loads early: consumed ~softmax-duration later
    bf16x8 vf[8];
#pragma unroll
    for (int d = 0; d < 4; ++d) {
      vf[2 * d] = *(const bf16x8*)(vptr + (size_t)(16 * d) * T_SEQ + kv0);
      vf[2 * d + 1] =
          *(const bf16x8*)(vptr + (size_t)(16 * d) * T_SEQ + kv0 + 32);
    }
    // QK^T (consumes kr loaded last iteration)
    f32x4 s[4] = {};
    __builtin_amdgcn_s_setprio(1);
#pragma unroll
    for (int f = 0; f < 4; ++f) {
      s[f] = __builtin_amdgcn_mfma_f32_16x16x32_bf16(kr[2 * f], qf0, s[f], 0, 0, 0);
      s[f] =
          __builtin_amdgcn_mfma_f32_16x16x32_bf16(kr[2 * f + 1], qf1, s[f], 0, 0, 0);
    }
    __builtin_amdgcn_s_setprio(0);
    // prefetch next K tile into just-freed kr (hidden under softmax+PV)
    if (it + 1 < nIter) {
      const uint16_t* knext = kptr + (size_t)(kv0 + 64) * rs;
#pragma unroll
      for (int f = 0; f < 4; ++f) {
        kr[2 * f] = *(const bf16x8*)(knext + (size_t)(16 * f) * rs);
        kr[2 * f + 1] = *(const bf16x8*)(knext + (size_t)(16 * f) * rs + 32);
      }
    }
    // mask only on the final iteration (provably unmasked before)
    float sv[16];
    if (it == nIter - 1) {
      const int kb = kv0 + 4 * hi;
#pragma unroll
      for (int f = 0; f < 4; ++f)
#pragma unroll
        for (int r = 0; r < 4; ++r)
          sv[4 * f + r] = (kb + 16 * f + r <= qg) ? s[f][r] : -1e30f;
    } else {
#pragma unroll
      for (int f = 0; f < 4; ++f)
#pragma unroll
        for (int r = 0; r < 4; ++r) sv[4 * f + r] = s[f][r];
    }
    // in-lane max, defer-max: rescale only when some lane's max grew
    float m0 = fmaxf(fmaxf(sv[0], sv[1]), fmaxf(sv[2], sv[3]));
    float m1 = fmaxf(fmaxf(sv[4], sv[5]), fmaxf(sv[6], sv[7]));
    float m2 = fmaxf(fmaxf(sv[8], sv[9]), fmaxf(sv[10], sv[11]));
    float m3 = fmaxf(fmaxf(sv[12], sv[13]), fmaxf(sv[14], sv[15]));
    float tmax = fmaxf(fmaxf(m0, m1), fmaxf(m2, m3));
    if (__any(tmax > m_run)) {
      float tm = fmaxf(tmax, __shfl_xor(tmax, 16));
      tm = fmaxf(tm, __shfl_xor(tm, 32));
      float m_new = fmaxf(m_run, tm);
      float corr = __expf(m_run - m_new);
      m_run = m_new;
      l_part *= corr;
#pragma unroll
      for (int d = 0; d < 4; ++d) acc[d] *= corr;
    }
    float pv[16];
#pragma unroll
    for (int i2 = 0; i2 < 16; ++i2) pv[i2] = __expf(sv[i2] - m_run);
    float s01 = (pv[0] + pv[1]) + (pv[2] + pv[3]);
    float s23 = (pv[4] + pv[5]) + (pv[6] + pv[7]);
    float s45 = (pv[8] + pv[9]) + (pv[10] + pv[11]);
    float s67 = (pv[12] + pv[13]) + (pv[14] + pv[15]);
    l_part += (s01 + s23) + (s45 + s67);
    // pack P to bf16 pairs (keys 16f+4hi+{0,1} / {2,3})
    uint32_t wp[8];
#pragma unroll
    for (int f = 0; f < 4; ++f) {
      asm("v_cvt_pk_bf16_f32 %0, %1, %2"
          : "=v"(wp[2 * f]) : "v"(pv[4 * f]), "v"(pv[4 * f + 1]));
      asm("v_cvt_pk_bf16_f32 %0, %1, %2"
          : "=v"(wp[2 * f + 1]) : "v"(pv[4 * f + 2]), "v"(pv[4 * f + 3]));
    }
    // redistribute to PV B-frag (lane gets keys 8hi..8hi+7)
    union { uint32_t u[4]; bf16x8 v; } pf0, pf1;
    {
      uint32_t a0 = __shfl((int)wp[0], sl0), b0 = __shfl((int)wp[2], sl0);
      uint32_t a1 = __shfl((int)wp[1], sl0), b1 = __shfl((int)wp[3], sl0);
      uint32_t a2 = __shfl((int)wp[0], sl1), b2 = __shfl((int)wp[2], sl1);
      uint32_t a3 = __shfl((int)wp[1], sl1), b3 = __shfl((int)wp[3], sl1);
      pf0.u[0] = lo ? a0 : b0; pf0.u[1] = lo ? a1 : b1;
      pf0.u[2] = lo ? a2 : b2; pf0.u[3] = lo ? a3 : b3;
    }
    {
      uint32_t a0 = __shfl((int)wp[4], sl0), b0 = __shfl((int)wp[6], sl0);
      uint32_t a1 = __shfl((int)wp[5], sl0), b1 = __shfl((int)wp[7], sl0);
      uint32_t a2 = __shfl((int)wp[4], sl1), b2 = __shfl((int)wp[6], sl1);
      uint32_t a3 = __shfl((int)wp[5], sl1), b3 = __shfl((int)wp[7], sl1);
      pf1.u[0] = lo ? a0 : b0; pf1.u[1] = lo ? a1 : b1;
      pf1.u[2] = lo ? a2 : b2; pf1.u[3] = lo ? a3 : b3;
    }
    // PV: O^T += V^T * P^T
    __builtin_amdgcn_s_setprio(1);
#pragma unroll
    for (int d = 0; d < 4; ++d)
      acc[d] =
          __builtin_amdgcn_mfma_f32_16x16x32_bf16(vf[2 * d], pf0.v, acc[d], 0, 0, 0);
#pragma unroll
    for (int d = 0; d < 4; ++d)
      acc[d] = __builtin_amdgcn_mfma_f32_16x16x32_bf16(vf[2 * d + 1], pf1.v,
                                                       acc[d], 0, 0, 0);
    __builtin_amdgcn_s_setprio(0);
  }
  float lt = l_part + __shfl_xor(l_part, 16);
  lt += __shfl_xor(lt, 32);
  float inv = 1.0f / lt;
  uint16_t* yrow = y + (size_t)(b * T_SEQ + qg) * N_EMBD + h * 64;
#pragma unroll
  for (int d = 0; d < 4; ++d) {
    uint32_t o01, o23;
    float v0 = acc[d][0] * inv, v1 = acc[d][1] * inv;
    float v2 = acc[d][2] * inv, v3 = acc[d][3] * inv;
    asm("v_cvt_pk_bf16_f32 %0, %1, %2" : "=v"(o01) : "v"(v0), "v"(v1));
    asm("v_cvt_pk_bf16_f32 %0, %1, %2" : "=v"(o23) : "v"(v2), "v"(v3));
    *(uint32_t*)(yrow + d * 16 + hi * 4) = o01;
    *(uint32_t*)(yrow + d * 16 + hi * 4 + 2) = o23;
  }
}

__global__ __launch_bounds__(256) void attn_kernel(
    const uint16_t* __restrict__ qkv, const uint16_t* __restrict__ Vt,
    uint16_t* __restrict__ y) {
  int tid = threadIdx.x;
  int w = tid >> 6, l = tid & 63;
  int ql = l & 15, hi = l >> 4;
  // XCD-aware remap: linear id = x + 16*y round-robins over 8 XCDs (id&7).
  // Give each XCD 4 bh values -> per-XCD K/V working set 2 MB (fits 4MB L2).
  int id = blockIdx.x + (int)gridDim.x * blockIdx.y;  // 0..511
  int xcd = id & 7;
  int slot = id >> 3;        // 0..63
  int bh = xcd * 4 + (slot & 3);
  int sp = slot >> 2;        // 0..15 strip-pair group
  int b = bh >> 4, h = bh & 15;
  int sA = sp * 4 + w;       // 0..63
  int q0A = sA * 16;
  int q0B = (127 - sA) * 16;  // complement strip: uniform total work
  const size_t rs = 3 * N_EMBD;
  const uint16_t* Qb = qkv + (size_t)(b * T_SEQ) * rs + h * 64;
  const uint16_t* Kb = Qb + N_EMBD;
  const uint16_t* Vb = Vt + (size_t)bh * 64 * T_SEQ;
  bool lo = hi < 2;
  int sl0 = ql + ((hi & 1) << 5);
  int sl1 = sl0 + 16;
  attn_strip(Qb, Kb, Vb, y, b, h, q0A, ql, hi, lo, sl0, sl1);
  attn_strip(Qb, Kb, Vb, y, b, h, q0B, ql, hi, lo, sl0, sl1);
}

extern "C" void kernel_launch(void* const* d_in, const int* in_sizes, int n_in,
                              void* d_out, int out_size, void* d_ws,
                              size_t ws_size, hipStream_t stream) {
  const float* x = (const float*)d_in[0];
  const float* Wqkv = (const float*)d_in[1];
  const float* bqkv = (const float*)d_in[2];
  const float* Wproj = (const float*)d_in[3];
  const float* bproj = (const float*)d_in[4];
  float* out = (float*)d_out;

  uint8_t* ws = (uint8_t*)d_ws;
  uint16_t* xb = (uint16_t*)(ws);                       //  8 MB: x bf16 [4096][1024]
  uint16_t* wqkvT = (uint16_t*)(ws + (8u << 20));       //  6 MB: Wqkv^T [3072][1024]
  uint16_t* wprojT = (uint16_t*)(ws + (14u << 20));     //  2 MB: Wproj^T [1024][1024]
  uint16_t* qkv = (uint16_t*)(ws + (16u << 20));        // 24 MB: qkv [4096][3072]
  uint16_t* vt = (uint16_t*)(ws + (40u << 20));         //  8 MB: V^T [32][64][2048]
  uint16_t* yb = (uint16_t*)(ws + (48u << 20));         //  8 MB: y [4096][1024]

  convert_f32_bf16<<<dim3(4096), dim3(256), 0, stream>>>(x, xb,
                                                         M_TOK * N_EMBD);
  transpose_convert<<<dim3(3072 / 64, 1024 / 64), dim3(256), 0, stream>>>(
      Wqkv, wqkvT, 1024, 3072);
  transpose_convert<<<dim3(1024 / 64, 1024 / 64), dim3(256), 0, stream>>>(
      Wproj, wprojT, 1024, 1024);
  gemm_bt<1><<<dim3(M_TOK / 128, 3072 / 128), dim3(256), 0, stream>>>(
      xb, wqkvT, bqkv, qkv, M_TOK, 3072, 1024);
  transpose_v<<<dim3(T_SEQ / 64, 32), dim3(256), 0, stream>>>(qkv, vt);
  attn_kernel<<<dim3(T_SEQ / 128, 32), dim3(256), 0, stream>>>(qkv, vt, yb);
  gemm_bt<0><<<dim3(M_TOK / 128, 1024 / 128), dim3(256), 0, stream>>>(
      yb, wprojT, bproj, out, M_TOK, 1024, 1024);
}

// Round 5
// 199.615 us; speedup vs baseline: 1.6166x; 1.0741x over previous
//
#include <hip/hip_runtime.h>
#include <hip/hip_bf16.h>
#include <stdint.h>

#define N_EMBD 1024
#define N_HEAD 16
#define HEAD_DIM 64
#define T_SEQ 2048
#define BATCH 2
#define M_TOK (BATCH * T_SEQ)  // 4096

typedef short bf16x8 __attribute__((ext_vector_type(8)));
typedef float f32x4 __attribute__((ext_vector_type(4)));

__device__ __forceinline__ void gload_lds16(const void* g, void* l) {
  __builtin_amdgcn_global_load_lds(
      (const __attribute__((address_space(1))) void*)g,
      (__attribute__((address_space(3))) void*)l, 16, 0, 0);
}

__device__ __forceinline__ uint16_t f2bf(float x) {
  uint32_t u = __float_as_uint(x);
  uint32_t r = (u + 0x7FFFu + ((u >> 16) & 1u)) >> 16;
  return (uint16_t)r;
}

// ---------------- elementwise f32 -> bf16 ----------------
__global__ void convert_f32_bf16(const float* __restrict__ in,
                                 uint16_t* __restrict__ out, int n) {
  int i = (blockIdx.x * blockDim.x + threadIdx.x) * 4;
  int stride = gridDim.x * blockDim.x * 4;
  for (; i + 3 < n; i += stride) {
    float4 v = *(const float4*)(in + i);
    ushort4 o;
    o.x = f2bf(v.x); o.y = f2bf(v.y); o.z = f2bf(v.z); o.w = f2bf(v.w);
    *(ushort4*)(out + i) = o;
  }
}

// ---------------- transpose + convert: W [R][C] f32 -> Wt [C][R] bf16 ------
__global__ void transpose_convert(const float* __restrict__ W,
                                  uint16_t* __restrict__ Wt, int R, int C_) {
  __shared__ uint16_t t[64][65];
  int c0 = blockIdx.x * 64, r0 = blockIdx.y * 64;
  int lc = threadIdx.x & 63, lr4 = threadIdx.x >> 6;
#pragma unroll
  for (int rr = 0; rr < 16; ++rr) {
    int r = rr * 4 + lr4;
    t[r][lc] = f2bf(W[(size_t)(r0 + r) * C_ + c0 + lc]);
  }
  __syncthreads();
#pragma unroll
  for (int rr = 0; rr < 16; ++rr) {
    int r = rr * 4 + lr4;  // output row within tile (= source column)
    Wt[(size_t)(c0 + r) * R + r0 + lc] = t[lc][r];
  }
}

// ---------------- V slice of qkv -> Vt [BH][64][T] ----------------
__global__ void transpose_v(const uint16_t* __restrict__ qkv,
                            uint16_t* __restrict__ Vt) {
  __shared__ uint16_t t[64][65];
  int t0 = blockIdx.x * 64;
  int bh = blockIdx.y;
  int b = bh >> 4, h = bh & 15;
  int lc = threadIdx.x & 63, lr4 = threadIdx.x >> 6;
  const uint16_t* src =
      qkv + (size_t)(b * T_SEQ) * (3 * N_EMBD) + 2 * N_EMBD + h * 64;
#pragma unroll
  for (int rr = 0; rr < 16; ++rr) {
    int r = rr * 4 + lr4;  // t index within tile
    t[r][lc] = src[(size_t)(t0 + r) * (3 * N_EMBD) + lc];
  }
  __syncthreads();
  uint16_t* dst = Vt + (size_t)bh * 64 * T_SEQ;
#pragma unroll
  for (int rr = 0; rr < 16; ++rr) {
    int d = rr * 4 + lr4;
    dst[(size_t)d * T_SEQ + t0 + lc] = t[lc][d];
  }
}

// ---------------- GEMM: C[M][N] = A[M][K] * Bt[N][K]^T + bias ----------------
template <int OUT_BF16>
__global__ __launch_bounds__(256) void gemm_bt(
    const uint16_t* __restrict__ A, const uint16_t* __restrict__ Bt,
    const float* __restrict__ bias, void* __restrict__ Cv, int M, int N,
    int K) {
  __shared__ __attribute__((aligned(16))) uint16_t sA[128 * 32];
  __shared__ __attribute__((aligned(16))) uint16_t sB[128 * 32];
  int tid = threadIdx.x;
  int w = tid >> 6, l = tid & 63;
  int wm = w >> 1, wn = w & 1;
  int ql = l & 15, hi = l >> 4;
  size_t m0 = (size_t)blockIdx.x * 128, n0 = (size_t)blockIdx.y * 128;
  f32x4 acc[4][4] = {};

  for (int kt = 0; kt < K; kt += 32) {
#pragma unroll
    for (int r = 0; r < 2; ++r) {
      int base = r * 256 + (w << 6);  // wave-uniform 16B-unit index
      int idx = base + l;
      gload_lds16(A + (m0 + (idx >> 2)) * K + kt + (idx & 3) * 8, sA + base * 8);
      gload_lds16(Bt + (n0 + (idx >> 2)) * K + kt + (idx & 3) * 8, sB + base * 8);
    }
    __syncthreads();
    bf16x8 af[4], bfr[4];
#pragma unroll
    for (int i = 0; i < 4; i++)
      af[i] = *(const bf16x8*)(sA + (wm * 64 + i * 16 + ql) * 32 + hi * 8);
#pragma unroll
    for (int j = 0; j < 4; j++)
      bfr[j] = *(const bf16x8*)(sB + (wn * 64 + j * 16 + ql) * 32 + hi * 8);
#pragma unroll
    for (int i = 0; i < 4; i++)
#pragma unroll
      for (int j = 0; j < 4; j++)
        acc[i][j] = __builtin_amdgcn_mfma_f32_16x16x32_bf16(af[i], bfr[j],
                                                            acc[i][j], 0, 0, 0);
    __syncthreads();
  }

#pragma unroll
  for (int i = 0; i < 4; i++) {
    size_t m = m0 + wm * 64 + i * 16 + hi * 4;
#pragma unroll
    for (int j = 0; j < 4; j++) {
      size_t n = n0 + wn * 64 + j * 16 + ql;
      float bv = bias[n];
#pragma unroll
      for (int r = 0; r < 4; r++) {
        float v = acc[i][j][r] + bv;
        if (OUT_BF16)
          ((uint16_t*)Cv)[(m + r) * N + n] = f2bf(v);
        else
          ((float*)Cv)[(m + r) * N + n] = v;
      }
    }
  }
}

// ---------------- causal flash attention (v5) ------------------------------
// Joint strip-pair: each wave processes strips s and 127-s in ONE kv loop;
// overlapped iterations share K/V loads between two QK/PV pipelines.
// __launch_bounds__(256,2) unlocks 256 VGPRs so all loads stay in flight.
__device__ __forceinline__ void load_q(const uint16_t* __restrict__ Qb, int qg,
                                       int hi, bf16x8& q0, bf16x8& q1) {
  const size_t rs = 3 * N_EMBD;
  q0 = *(const bf16x8*)(Qb + (size_t)qg * rs + hi * 8);
  q1 = *(const bf16x8*)(Qb + (size_t)qg * rs + 32 + hi * 8);
  // fold scale = 1/8 into Q's bf16 exponent (exact; flush tiny exps to 0)
#pragma unroll
  for (int j = 0; j < 8; ++j) {
    uint16_t u = (uint16_t)q0[j];
    q0[j] = (short)(((u & 0x7f80u) >= 0x180u) ? (u - 0x180u) : (u & 0x8000u));
    uint16_t v = (uint16_t)q1[j];
    q1[j] = (short)(((v & 0x7f80u) >= 0x180u) ? (v - 0x180u) : (v & 0x8000u));
  }
}

__device__ __forceinline__ void sm_pv_step(const f32x4* __restrict__ s,
                                           f32x4* __restrict__ acc,
                                           float& m_run, float& l_part,
                                           const bf16x8* __restrict__ vf,
                                           bool mask, int kb, int qg, bool lo,
                                           int sl0, int sl1) {
  float sv[16];
  if (mask) {
#pragma unroll
    for (int f = 0; f < 4; ++f)
#pragma unroll
      for (int r = 0; r < 4; ++r)
        sv[4 * f + r] = (kb + 16 * f + r <= qg) ? s[f][r] : -1e30f;
  } else {
#pragma unroll
    for (int f = 0; f < 4; ++f)
#pragma unroll
      for (int r = 0; r < 4; ++r) sv[4 * f + r] = s[f][r];
  }
  float m0 = fmaxf(fmaxf(sv[0], sv[1]), fmaxf(sv[2], sv[3]));
  float m1 = fmaxf(fmaxf(sv[4], sv[5]), fmaxf(sv[6], sv[7]));
  float m2 = fmaxf(fmaxf(sv[8], sv[9]), fmaxf(sv[10], sv[11]));
  float m3 = fmaxf(fmaxf(sv[12], sv[13]), fmaxf(sv[14], sv[15]));
  float tmax = fmaxf(fmaxf(m0, m1), fmaxf(m2, m3));
  if (__any(tmax > m_run)) {
    float tm = fmaxf(tmax, __shfl_xor(tmax, 16));
    tm = fmaxf(tm, __shfl_xor(tm, 32));
    float m_new = fmaxf(m_run, tm);
    float corr = __expf(m_run - m_new);
    m_run = m_new;
    l_part *= corr;
#pragma unroll
    for (int d = 0; d < 4; ++d) acc[d] *= corr;
  }
  float pv[16];
#pragma unroll
  for (int i2 = 0; i2 < 16; ++i2) pv[i2] = __expf(sv[i2] - m_run);
  float s01 = (pv[0] + pv[1]) + (pv[2] + pv[3]);
  float s23 = (pv[4] + pv[5]) + (pv[6] + pv[7]);
  float s45 = (pv[8] + pv[9]) + (pv[10] + pv[11]);
  float s67 = (pv[12] + pv[13]) + (pv[14] + pv[15]);
  l_part += (s01 + s23) + (s45 + s67);
  uint32_t wp[8];
#pragma unroll
  for (int f = 0; f < 4; ++f) {
    asm("v_cvt_pk_bf16_f32 %0, %1, %2"
        : "=v"(wp[2 * f]) : "v"(pv[4 * f]), "v"(pv[4 * f + 1]));
    asm("v_cvt_pk_bf16_f32 %0, %1, %2"
        : "=v"(wp[2 * f + 1]) : "v"(pv[4 * f + 2]), "v"(pv[4 * f + 3]));
  }
  union { uint32_t u[4]; bf16x8 v; } pf0, pf1;
  {
    uint32_t a0 = __shfl((int)wp[0], sl0), b0 = __shfl((int)wp[2], sl0);
    uint32_t a1 = __shfl((int)wp[1], sl0), b1 = __shfl((int)wp[3], sl0);
    uint32_t a2 = __shfl((int)wp[0], sl1), b2 = __shfl((int)wp[2], sl1);
    uint32_t a3 = __shfl((int)wp[1], sl1), b3 = __shfl((int)wp[3], sl1);
    pf0.u[0] = lo ? a0 : b0; pf0.u[1] = lo ? a1 : b1;
    pf0.u[2] = lo ? a2 : b2; pf0.u[3] = lo ? a3 : b3;
  }
  {
    uint32_t a0 = __shfl((int)wp[4], sl0), b0 = __shfl((int)wp[6], sl0);
    uint32_t a1 = __shfl((int)wp[5], sl0), b1 = __shfl((int)wp[7], sl0);
    uint32_t a2 = __shfl((int)wp[4], sl1), b2 = __shfl((int)wp[6], sl1);
    uint32_t a3 = __shfl((int)wp[5], sl1), b3 = __shfl((int)wp[7], sl1);
    pf1.u[0] = lo ? a0 : b0; pf1.u[1] = lo ? a1 : b1;
    pf1.u[2] = lo ? a2 : b2; pf1.u[3] = lo ? a3 : b3;
  }
  __builtin_amdgcn_s_setprio(1);
#pragma unroll
  for (int d = 0; d < 4; ++d)
    acc[d] =
        __builtin_amdgcn_mfma_f32_16x16x32_bf16(vf[2 * d], pf0.v, acc[d], 0, 0, 0);
#pragma unroll
  for (int d = 0; d < 4; ++d)
    acc[d] = __builtin_amdgcn_mfma_f32_16x16x32_bf16(vf[2 * d + 1], pf1.v,
                                                     acc[d], 0, 0, 0);
  __builtin_amdgcn_s_setprio(0);
}

__device__ __forceinline__ void write_out(const f32x4* __restrict__ acc,
                                          float l_part,
                                          uint16_t* __restrict__ y, int b,
                                          int h, int qg, int hi) {
  float lt = l_part + __shfl_xor(l_part, 16);
  lt += __shfl_xor(lt, 32);
  float inv = 1.0f / lt;
  uint16_t* yrow = y + (size_t)(b * T_SEQ + qg) * N_EMBD + h * 64;
#pragma unroll
  for (int d = 0; d < 4; ++d) {
    uint32_t o01, o23;
    float v0 = acc[d][0] * inv, v1 = acc[d][1] * inv;
    float v2 = acc[d][2] * inv, v3 = acc[d][3] * inv;
    asm("v_cvt_pk_bf16_f32 %0, %1, %2" : "=v"(o01) : "v"(v0), "v"(v1));
    asm("v_cvt_pk_bf16_f32 %0, %1, %2" : "=v"(o23) : "v"(v2), "v"(v3));
    *(uint32_t*)(yrow + d * 16 + hi * 4) = o01;
    *(uint32_t*)(yrow + d * 16 + hi * 4 + 2) = o23;
  }
}

__global__ __launch_bounds__(256, 2) void attn_kernel(
    const uint16_t* __restrict__ qkv, const uint16_t* __restrict__ Vt,
    uint16_t* __restrict__ y) {
  int tid = threadIdx.x;
  int w = tid >> 6, l = tid & 63;
  int ql = l & 15, hi = l >> 4;
  // XCD-aware remap: each XCD owns 4 bh values (K/V set 2MB fits 4MB L2).
  int id = blockIdx.x + (int)gridDim.x * blockIdx.y;  // 0..511
  int xcd = id & 7;
  int slot = id >> 3;        // 0..63
  int bh = xcd * 4 + (slot & 3);
  int sp = slot >> 2;        // 0..15 strip-pair group
  int b = bh >> 4, h = bh & 15;
  int sA = sp * 4 + w;       // 0..63
  int qA = sA * 16;          // short strip base
  int qB = (127 - sA) * 16;  // long strip base (complement)
  const size_t rs = 3 * N_EMBD;
  const uint16_t* Qb = qkv + (size_t)(b * T_SEQ) * rs + h * 64;
  const uint16_t* Kb = Qb + N_EMBD;
  const uint16_t* Vb = Vt + (size_t)bh * 64 * T_SEQ;
  bool lo = hi < 2;
  int sl0 = ql + ((hi & 1) << 5);
  int sl1 = sl0 + 16;

  bf16x8 qfA0, qfA1, qfB0, qfB1;
  load_q(Qb, qA + ql, hi, qfA0, qfA1);
  load_q(Qb, qB + ql, hi, qfB0, qfB1);

  f32x4 accA[4] = {}, accB[4] = {};
  float mA = -1e30f, lA = 0.f, mB = -1e30f, lB = 0.f;
  const int nA = (qA + 79) >> 6;  // 1..16
  const int nB = (qB + 79) >> 6;  // 17..32
  const uint16_t* kptr = Kb + (size_t)ql * rs + hi * 8;
  const uint16_t* vptr = Vb + (size_t)ql * T_SEQ + hi * 8;

  bf16x8 kr[8];
#pragma unroll
  for (int f = 0; f < 4; ++f) {
    kr[2 * f] = *(const bf16x8*)(kptr + (size_t)(16 * f) * rs);
    kr[2 * f + 1] = *(const bf16x8*)(kptr + (size_t)(16 * f) * rs + 32);
  }

  for (int it = 0; it < nB; ++it) {
    const int kv0 = it << 6;
    const bool actA = it < nA;  // wave-uniform
    // V loads (shared by both strips)
    bf16x8 vf[8];
#pragma unroll
    for (int d = 0; d < 4; ++d) {
      vf[2 * d] = *(const bf16x8*)(vptr + (size_t)(16 * d) * T_SEQ + kv0);
      vf[2 * d + 1] =
          *(const bf16x8*)(vptr + (size_t)(16 * d) * T_SEQ + kv0 + 32);
    }
    // QK^T for both strips off the same kr
    f32x4 sA_[4] = {}, sB_[4] = {};
    __builtin_amdgcn_s_setprio(1);
    if (actA) {
#pragma unroll
      for (int f = 0; f < 4; ++f) {
        sA_[f] =
            __builtin_amdgcn_mfma_f32_16x16x32_bf16(kr[2 * f], qfA0, sA_[f], 0, 0, 0);
        sA_[f] = __builtin_amdgcn_mfma_f32_16x16x32_bf16(kr[2 * f + 1], qfA1,
                                                         sA_[f], 0, 0, 0);
      }
    }
#pragma unroll
    for (int f = 0; f < 4; ++f) {
      sB_[f] =
          __builtin_amdgcn_mfma_f32_16x16x32_bf16(kr[2 * f], qfB0, sB_[f], 0, 0, 0);
      sB_[f] = __builtin_amdgcn_mfma_f32_16x16x32_bf16(kr[2 * f + 1], qfB1,
                                                       sB_[f], 0, 0, 0);
    }
    __builtin_amdgcn_s_setprio(0);
    // prefetch next K tile (hidden under softmax+PV)
    if (it + 1 < nB) {
      const uint16_t* knext = kptr + (size_t)(kv0 + 64) * rs;
#pragma unroll
      for (int f = 0; f < 4; ++f) {
        kr[2 * f] = *(const bf16x8*)(knext + (size_t)(16 * f) * rs);
        kr[2 * f + 1] = *(const bf16x8*)(knext + (size_t)(16 * f) * rs + 32);
      }
    }
    const int kb = kv0 + 4 * hi;
    if (actA)
      sm_pv_step(sA_, accA, mA, lA, vf, it == nA - 1, kb, qA + ql, lo, sl0, sl1);
    sm_pv_step(sB_, accB, mB, lB, vf, it == nB - 1, kb, qB + ql, lo, sl0, sl1);
  }

  write_out(accA, lA, y, b, h, qA + ql, hi);
  write_out(accB, lB, y, b, h, qB + ql, hi);
}

extern "C" void kernel_launch(void* const* d_in, const int* in_sizes, int n_in,
                              void* d_out, int out_size, void* d_ws,
                              size_t ws_size, hipStream_t stream) {
  const float* x = (const float*)d_in[0];
  const float* Wqkv = (const float*)d_in[1];
  const float* bqkv = (const float*)d_in[2];
  const float* Wproj = (const float*)d_in[3];
  const float* bproj = (const float*)d_in[4];
  float* out = (float*)d_out;

  uint8_t* ws = (uint8_t*)d_ws;
  uint16_t* xb = (uint16_t*)(ws);                       //  8 MB: x bf16 [4096][1024]
  uint16_t* wqkvT = (uint16_t*)(ws + (8u << 20));       //  6 MB: Wqkv^T [3072][1024]
  uint16_t* wprojT = (uint16_t*)(ws + (14u << 20));     //  2 MB: Wproj^T [1024][1024]
  uint16_t* qkv = (uint16_t*)(ws + (16u << 20));        // 24 MB: qkv [4096][3072]
  uint16_t* vt = (uint16_t*)(ws + (40u << 20));         //  8 MB: V^T [32][64][2048]
  uint16_t* yb = (uint16_t*)(ws + (48u << 20));         //  8 MB: y [4096][1024]

  convert_f32_bf16<<<dim3(4096), dim3(256), 0, stream>>>(x, xb,
                                                         M_TOK * N_EMBD);
  transpose_convert<<<dim3(3072 / 64, 1024 / 64), dim3(256), 0, stream>>>(
      Wqkv, wqkvT, 1024, 3072);
  transpose_convert<<<dim3(1024 / 64, 1024 / 64), dim3(256), 0, stream>>>(
      Wproj, wprojT, 1024, 1024);
  gemm_bt<1><<<dim3(M_TOK / 128, 3072 / 128), dim3(256), 0, stream>>>(
      xb, wqkvT, bqkv, qkv, M_TOK, 3072, 1024);
  transpose_v<<<dim3(T_SEQ / 64, 32), dim3(256), 0, stream>>>(qkv, vt);
  attn_kernel<<<dim3(T_SEQ / 128, 32), dim3(256), 0, stream>>>(qkv, vt, yb);
  gemm_bt<0><<<dim3(M_TOK / 128, 1024 / 128), dim3(256), 0, stream>>>(
      yb, wprojT, bproj, out, M_TOK, 1024, 1024);
}